// Round 5
// baseline (459.856 us; speedup 1.0000x reference)
//
#include <hip/hip_runtime.h>

#define G      1024
#define NNODES 65536
#define NEDGES 262144
#define D      256
#define DIN    768
#define DHID   512
#define DOUT   256
#define CW     512            // collected row width: [edge_agg | node_agg]

// ---------------------------------------------------------------------------
// Aggregation, atomic-free (r4, unchanged — control): one block per graph.
// Two structurally different agg implementations (r0 vs r4) tied within 1us
// -> this is at the ~55us BW floor (320MB @ ~6.3TB/s).
// ---------------------------------------------------------------------------

__device__ __forceinline__ int lb_sorted(const int* __restrict__ a, int n, int v) {
    int lo = 0, hi = n;
    while (lo < hi) { int m = (lo + hi) >> 1; if (a[m] < v) lo = m + 1; else hi = m; }
    return lo;
}

__device__ __forceinline__ float4 seg_sum_rows(const float4* __restrict__ src,
                                               int s, int e, int w, int lane) {
    float4 acc = {0.f, 0.f, 0.f, 0.f};
    const int n = e - s;
    const int ngrp = n >> 2;
    for (int gi = w; gi < ngrp; gi += 4) {
        const float4* p = src + (size_t)(s + gi * 4) * (D / 4) + lane;
        const float4 v0 = p[0];
        const float4 v1 = p[D / 4];
        const float4 v2 = p[2 * (D / 4)];
        const float4 v3 = p[3 * (D / 4)];
        acc.x += (v0.x + v1.x) + (v2.x + v3.x);
        acc.y += (v0.y + v1.y) + (v2.y + v3.y);
        acc.z += (v0.z + v1.z) + (v2.z + v3.z);
        acc.w += (v0.w + v1.w) + (v2.w + v3.w);
    }
    if (w == 0) {
        for (int r = s + (ngrp << 2); r < e; ++r) {
            const float4 v = src[(size_t)r * (D / 4) + lane];
            acc.x += v.x; acc.y += v.y; acc.z += v.z; acc.w += v.w;
        }
    }
    return acc;
}

__global__ __launch_bounds__(256, 4) void agg_per_graph(
        const float4* __restrict__ nodes,
        const float4* __restrict__ edges,
        const int* __restrict__ nids,
        const int* __restrict__ eids,
        float* __restrict__ collected) {
    __shared__ int seg[4];
    __shared__ float ered[4][256];
    __shared__ float nred[4][256];

    const int tid  = threadIdx.x;
    const int lane = tid & 63;
    const int w    = tid >> 6;
    const int g    = blockIdx.x;

    if (tid < 4) {
        const int* a = (tid < 2) ? eids : nids;
        const int  n = (tid < 2) ? NEDGES : NNODES;
        seg[tid] = lb_sorted(a, n, g + (tid & 1));
    }
    __syncthreads();
    const int es = seg[0], ee = seg[1], ns = seg[2], ne = seg[3];

    const float4 ea = seg_sum_rows(edges, es, ee, w, lane);
    const float4 na = seg_sum_rows(nodes, ns, ne, w, lane);

    *(float4*)&ered[w][lane * 4] = ea;
    *(float4*)&nred[w][lane * 4] = na;
    __syncthreads();

    const float ev = (ered[0][tid] + ered[1][tid]) + (ered[2][tid] + ered[3][tid]);
    const float nv = (nred[0][tid] + nred[1][tid]) + (nred[2][tid] + nred[3][tid]);
    collected[(size_t)g * CW + tid]       = ev;
    collected[(size_t)g * CW + 256 + tid] = nv;
}

// ---------------------------------------------------------------------------
// GEMM1, 16x64 tiles -> grid (8,64) = 512 blocks = 2 INDEPENDENT blocks/CU.
// Single-variable change vs r4 (was 32x64, 256 blocks = 1 block/CU). Theory:
// GEMM section is parallelism-limited (r2: half coverage -> +24us; r1: more
// waves in the SAME block null, because barrier-coupled waves all stall on the
// same syncthreads+vmcnt drain). Independent blocks overlap freely: one runs
// its 32-k FMA loop while the other waits in barrier/global-prefetch. 256 thr,
// micro 1x4, k-major A in LDS, reg->LDS double buffer. A split: cols
// [0,asplit) from A1 (stride s1), [asplit,K) from A2 (stride s2).
// ---------------------------------------------------------------------------
__global__ __launch_bounds__(256) void gemm_bias_act16(
        const float* __restrict__ A1, const float* __restrict__ A2,
        const float* __restrict__ B,
        const float* __restrict__ bias, float* __restrict__ C,
        int N, int K, int asplit, int s1, int s2, int relu) {
    __shared__ float At[2][32][17];                  // k-major [k][m], m=0..15
    __shared__ __align__(16) float Bs[2][32][64];

    const int tid = threadIdx.x;
    const int tx = tid & 15;          // output col group (float4)
    const int ty = tid >> 4;          // output row 0..15
    const int m0 = blockIdx.y * 16;
    const int n0 = blockIdx.x * 64;

    const int ar = (tid >> 3) & 15;   // A-tile row (tid<128 active)
    const int ac = (tid & 7) * 4;     // A-tile k-offset (float4)
    const int br = tid >> 3;          // B-tile k-row 0..31
    const int bc = (tid & 7) * 8;     // B-tile col (2x float4)

    const int arow = m0 + ar;
    const float* Bptr = B + (size_t)br * N + n0 + bc;

    auto loadA = [&](int kc) -> float4 {
        return (kc < asplit) ? *(const float4*)&A1[(size_t)arow * s1 + kc + ac]
                             : *(const float4*)&A2[(size_t)arow * s2 + (kc - asplit) + ac];
    };

    {
        const float4 b40 = *(const float4*)Bptr;
        const float4 b41 = *(const float4*)(Bptr + 4);
        *(float4*)&Bs[0][br][bc]     = b40;
        *(float4*)&Bs[0][br][bc + 4] = b41;
        if (tid < 128) {
            const float4 a4 = loadA(0);
            At[0][ac + 0][ar] = a4.x; At[0][ac + 1][ar] = a4.y;
            At[0][ac + 2][ar] = a4.z; At[0][ac + 3][ar] = a4.w;
        }
    }
    __syncthreads();

    float4 acc = {0.f, 0.f, 0.f, 0.f};
    int buf = 0;

    for (int kt = 0; kt < K; kt += 32) {
        const bool has_next = (kt + 32) < K;
        float4 na, nb0, nb1;
        if (has_next) {
            nb0 = *(const float4*)(Bptr + (size_t)(kt + 32) * N);
            nb1 = *(const float4*)(Bptr + (size_t)(kt + 32) * N + 4);
            if (tid < 128) na = loadA(kt + 32);
        }
#pragma unroll
        for (int k = 0; k < 32; ++k) {
            const float a   = At[buf][k][ty];              // broadcast read
            const float4 bv = *(const float4*)&Bs[buf][k][tx * 4];
            acc.x += a * bv.x; acc.y += a * bv.y;
            acc.z += a * bv.z; acc.w += a * bv.w;
        }
        if (has_next) {
            const int nb = buf ^ 1;
            *(float4*)&Bs[nb][br][bc]     = nb0;
            *(float4*)&Bs[nb][br][bc + 4] = nb1;
            if (tid < 128) {
                At[nb][ac + 0][ar] = na.x; At[nb][ac + 1][ar] = na.y;
                At[nb][ac + 2][ar] = na.z; At[nb][ac + 3][ar] = na.w;
            }
            __syncthreads();
            buf = nb;
        }
    }

    const int col = n0 + tx * 4;
    const float4 bv = *(const float4*)&bias[col];
    float4 o;
    o.x = acc.x + bv.x; o.y = acc.y + bv.y;
    o.z = acc.z + bv.z; o.w = acc.w + bv.w;
    if (relu) {
        o.x = fmaxf(o.x, 0.f); o.y = fmaxf(o.y, 0.f);
        o.z = fmaxf(o.z, 0.f); o.w = fmaxf(o.w, 0.f);
    }
    *(float4*)&C[(size_t)(m0 + ty) * N + col] = o;
}

// ---------------------------------------------------------------------------
// GEMM2 (r4, unchanged — control): 16x64 tiles, grid (4,64) = 256 blocks.
// ---------------------------------------------------------------------------
__global__ __launch_bounds__(256) void gemm2_bias(
        const float* __restrict__ A, const float* __restrict__ B,
        const float* __restrict__ bias, float* __restrict__ C) {
    __shared__ float At[2][32][17];                  // k-major [k][m], m=0..15
    __shared__ __align__(16) float Bs[2][32][64];

    const int tid = threadIdx.x;
    const int tx = tid & 15;
    const int ty = tid >> 4;
    const int m0 = blockIdx.y * 16;
    const int n0 = blockIdx.x * 64;

    const int ar = (tid >> 3) & 15;
    const int ac = (tid & 7) * 4;
    const int br = tid >> 3;
    const int bc = (tid & 7) * 8;

    const float* Aptr = A + (size_t)(m0 + ar) * DHID + ac;
    const float* Bptr = B + (size_t)br * DOUT + n0 + bc;

    {
        const float4 b40 = *(const float4*)Bptr;
        const float4 b41 = *(const float4*)(Bptr + 4);
        *(float4*)&Bs[0][br][bc]     = b40;
        *(float4*)&Bs[0][br][bc + 4] = b41;
        if (tid < 128) {
            const float4 a4 = *(const float4*)Aptr;
            At[0][ac + 0][ar] = a4.x; At[0][ac + 1][ar] = a4.y;
            At[0][ac + 2][ar] = a4.z; At[0][ac + 3][ar] = a4.w;
        }
    }
    __syncthreads();

    float4 acc = {0.f, 0.f, 0.f, 0.f};
    int buf = 0;

    for (int kt = 0; kt < DHID; kt += 32) {
        const bool has_next = (kt + 32) < DHID;
        float4 na, nb0, nb1;
        if (has_next) {
            nb0 = *(const float4*)(Bptr + (size_t)(kt + 32) * DOUT);
            nb1 = *(const float4*)(Bptr + (size_t)(kt + 32) * DOUT + 4);
            if (tid < 128) na = *(const float4*)(Aptr + (kt + 32));
        }
#pragma unroll
        for (int k = 0; k < 32; ++k) {
            const float a   = At[buf][k][ty];
            const float4 bv = *(const float4*)&Bs[buf][k][tx * 4];
            acc.x += a * bv.x; acc.y += a * bv.y;
            acc.z += a * bv.z; acc.w += a * bv.w;
        }
        if (has_next) {
            const int nb = buf ^ 1;
            *(float4*)&Bs[nb][br][bc]     = nb0;
            *(float4*)&Bs[nb][br][bc + 4] = nb1;
            if (tid < 128) {
                At[nb][ac + 0][ar] = na.x; At[nb][ac + 1][ar] = na.y;
                At[nb][ac + 2][ar] = na.z; At[nb][ac + 3][ar] = na.w;
            }
            __syncthreads();
            buf = nb;
        }
    }

    const int col = n0 + tx * 4;
    const float4 bv = *(const float4*)&bias[col];
    float4 o;
    o.x = acc.x + bv.x; o.y = acc.y + bv.y;
    o.z = acc.z + bv.z; o.w = acc.w + bv.w;
    *(float4*)&C[(size_t)(m0 + ty) * DOUT + col] = o;
}

extern "C" void kernel_launch(void* const* d_in, const int* in_sizes, int n_in,
                              void* d_out, int out_size, void* d_ws, size_t ws_size,
                              hipStream_t stream) {
    const float* nodes    = (const float*)d_in[0];
    const float* edges    = (const float*)d_in[1];
    const float* globals_ = (const float*)d_in[2];
    const int*   nids     = (const int*)d_in[3];
    const int*   eids     = (const int*)d_in[4];
    const float* W1       = (const float*)d_in[5];
    const float* b1       = (const float*)d_in[6];
    const float* W2       = (const float*)d_in[7];
    const float* b2       = (const float*)d_in[8];
    float* out = (float*)d_out;

    float* collected = (float*)d_ws;                 // [G, 512] (2 MB), written exactly once
    float* h         = collected + (size_t)G * CW;   // [G, DHID] (2 MB), fully written

    agg_per_graph<<<G, 256, 0, stream>>>(
        (const float4*)nodes, (const float4*)edges, nids, eids, collected);

    // GEMM1: 16x64 tiles -> grid (8,64) = 512 blocks = 2 independent blocks/CU
    gemm_bias_act16<<<dim3(DHID / 64, G / 16), 256, 0, stream>>>(
        collected, globals_, W1, b1, h, DHID, DIN, CW, CW, D, 1);

    // GEMM2: 16x64 tiles -> grid (4,64) = 256 blocks (r4 control)
    gemm2_bias<<<dim3(DOUT / 64, G / 16), 256, 0, stream>>>(h, W2, b2, out);
}